// Round 5
// baseline (283.448 us; speedup 1.0000x reference)
//
#include <hip/hip_runtime.h>
#include <stdint.h>

#define HDIM 64
#define TDIM 512
#define GB   8     // batches per block (M rows actually used)
#define MR   16    // MFMA M-tile rows (padded; rows GB..15 stay zero)

// ---- MFMA timestep-parallel RNN, 2 blocks/CU for latency overlap ----
// Round-4 counters: 973 cy/step/block with MfmaUtil 10%, VALUBusy 34%,
// Occupancy 11% -> latency-chain-bound at 1 block/CU (the per-step serial
// chain barrier->ds_read->MFMA->tanh->ds_write->barrier has nothing to
// overlap with). Round-5: GB 16->8, grid 256->512 blocks = 2 independent
// blocks per CU; the two serial chains interleave on the same SIMDs.
// MFMA M-rows 8-15 are wasted (zero), but MFMA capacity is 90% idle --
// latency is the scarce resource, not matrix throughput.
//
// Per timestep t: h_new[8b x 64h] = tanh( xw + h[8b x 64k] @ W_hh^T )
// Block = 4 waves; wave w owns n-slice [16w..16w+15]:
//   D[16x16] = A[16x32] x B[32x16] (mfma_f32_16x16x32_f16), K=64 in 2 chunks.
// Precision: f16 hi/lo split on h and W (3 product terms, f32 acc).
// h ping-pongs through LDS; XOR swizzle ^((row&7)<<4) on the 128B-stride
// A reads; one __syncthreads per step.
//
// Fragment layouts (16x16x32, gfx950):
//   A: row m = lane&15, k = 8*(lane>>4)+e
//   B: col n = lane&15, k = 8*(lane>>4)+e
//   C/D: col n = lane&15, row m = 4*(lane>>4)+reg   [m89-verified]

typedef float     f32x4 __attribute__((ext_vector_type(4)));
typedef _Float16  f16x8 __attribute__((ext_vector_type(8)));

__global__ __launch_bounds__(256)
void rnn_mfma_ov2(const float* __restrict__ x,
                  const float* __restrict__ W_ih,
                  const float* __restrict__ W_hh,
                  const float* __restrict__ b_ih,
                  const float* __restrict__ b_hh,
                  const float* __restrict__ fc_w,
                  const float* __restrict__ fc_b,
                  float* __restrict__ out,
                  int B)
{
    // hh[pp][hi/lo][16 rows][64 cols] f16, byte-swizzled; 2KB per slice, 8KB total
    __shared__ unsigned short hh[2][2][MR * HDIM];
    __shared__ float xs[64][MR];          // x chunk [t_local][m]; cols 0..7 used
    __shared__ float red[4][GB];          // final reduction

    const int tid  = threadIdx.x;
    const int lane = tid & 63;
    const int wid  = tid >> 6;            // 0..3 : n-slice
    const int g    = lane >> 4;           // 0..3 : k-block / m-quad
    const int m16  = lane & 15;
    const int gb0  = blockIdx.x * GB;     // first batch of this block

    const int n = wid * 16 + m16;         // this lane's h_new column (0..63)

    // B-operand frags: W_hh^T[k][n] = W_hh[n][k]; lane needs k = 32c + 8g + e
    f16x8 Bhi[2], Blo[2];
#pragma unroll
    for (int c = 0; c < 2; ++c) {
        const float* wrow = W_hh + n * HDIM + 32 * c + 8 * g;
        const f32x4 wa = *(const f32x4*)(wrow);
        const f32x4 wb = *(const f32x4*)(wrow + 4);
#pragma unroll
        for (int e = 0; e < 4; ++e) {
            float f0 = wa[e], f1 = wb[e];
            _Float16 h0 = (_Float16)f0, h1 = (_Float16)f1;
            Bhi[c][e]     = h0;  Blo[c][e]     = (_Float16)(f0 - (float)h0);
            Bhi[c][e + 4] = h1;  Blo[c][e + 4] = (_Float16)(f1 - (float)h1);
        }
    }

    const float wih  = W_ih[n];                  // I == 1
    const float bias = b_ih[n] + b_hh[n];
    const float fcw  = fc_w[n];

    // A-frag read byte offsets (row m16, k = 32c + 8g), XOR-swizzled
    const int aoff0 = (m16 * 128 +  0 + 16 * g) ^ ((m16 & 7) << 4);
    const int aoff1 = (m16 * 128 + 64 + 16 * g) ^ ((m16 & 7) << 4);
    // h_new write byte offsets (row 4g+r, col n), same swizzle; rows<8 only
    int woff[4];
#pragma unroll
    for (int r = 0; r < 4; ++r) {
        const int wm = 4 * g + r;
        woff[r] = (wm * 128 + 2 * n) ^ ((wm & 7) << 4);
    }

    char* const hbase = (char*)hh;

    // zero BOTH ping-pong buffers (8KB): h(t=0)=0 AND padded rows 8..15
    // must stay zero forever (they are never written).
    ((f32x4*)hbase)[tid]       = (f32x4){0.f, 0.f, 0.f, 0.f};
    ((f32x4*)hbase)[tid + 256] = (f32x4){0.f, 0.f, 0.f, 0.f};
    // zero xs padding cols too (keeps garbage out of dead C-init lanes)
    ((f32x4*)xs)[tid] = (f32x4){0.f, 0.f, 0.f, 0.f};

    // x staging: 8 rows x 64 t = 128 f32x4 loads; threads 0..127
    const int sm = tid >> 4;              // batch row 0..7 (tid<128)
    const int tq = tid & 15;              // t-quad

    const float TWO_LOG2E = 2.885390081777927f;   // 2*log2(e)
    float hf0 = 0.f, hf1 = 0.f, hf2 = 0.f, hf3 = 0.f;

    for (int tc = 0; tc < TDIM / 64; ++tc) {
        if (tid < 128) {
            const f32x4 xv4 = *(const f32x4*)(x + (size_t)(gb0 + sm) * TDIM
                                                + tc * 64 + tq * 4);
            xs[tq * 4 + 0][sm] = xv4.x;
            xs[tq * 4 + 1][sm] = xv4.y;
            xs[tq * 4 + 2][sm] = xv4.z;
            xs[tq * 4 + 3][sm] = xv4.w;
        }
        __syncthreads();   // covers zero-init (tc==0) and xs staging

#pragma unroll 1
        for (int tj = 0; tj < 64; ++tj) {
            const int pp = tj & 1;                 // global parity (tc*64 even)
            const char* rb = hbase + pp * 4096;
            char*       wb = hbase + (pp ^ 1) * 4096;

            // A frags: h[m16][k] hi/lo, two K-chunks (rows 8-15 read zeros)
            const f16x8 Ahi0 = *(const f16x8*)(rb +        aoff0);
            const f16x8 Ahi1 = *(const f16x8*)(rb +        aoff1);
            const f16x8 Alo0 = *(const f16x8*)(rb + 2048 + aoff0);
            const f16x8 Alo1 = *(const f16x8*)(rb + 2048 + aoff1);

            // C init = xw for this lane's 4 rows m = 4g+r
            const f32x4 xv = *(const f32x4*)((const char*)xs + tj * 64 + 16 * g);
            f32x4 c1;
            c1.x = fmaf(xv.x, wih, bias);
            c1.y = fmaf(xv.y, wih, bias);
            c1.z = fmaf(xv.z, wih, bias);
            c1.w = fmaf(xv.w, wih, bias);
            f32x4 c2 = (f32x4){0.f, 0.f, 0.f, 0.f};
            f32x4 c3 = (f32x4){0.f, 0.f, 0.f, 0.f};

            // three 2-deep chains (latency) instead of one 6-deep
            c1 = __builtin_amdgcn_mfma_f32_16x16x32_f16(Ahi0, Bhi[0], c1, 0, 0, 0);
            c2 = __builtin_amdgcn_mfma_f32_16x16x32_f16(Ahi0, Blo[0], c2, 0, 0, 0);
            c3 = __builtin_amdgcn_mfma_f32_16x16x32_f16(Alo0, Bhi[0], c3, 0, 0, 0);
            c1 = __builtin_amdgcn_mfma_f32_16x16x32_f16(Ahi1, Bhi[1], c1, 0, 0, 0);
            c2 = __builtin_amdgcn_mfma_f32_16x16x32_f16(Ahi1, Blo[1], c2, 0, 0, 0);
            c3 = __builtin_amdgcn_mfma_f32_16x16x32_f16(Alo1, Bhi[1], c3, 0, 0, 0);

            // epilogue: rows 4g+r valid only for g<2 (GB=8)
            if (g < 2) {
#pragma unroll
                for (int r = 0; r < 4; ++r) {
                    const float z = c1[r] + (c2[r] + c3[r]);
                    const float e = __builtin_amdgcn_exp2f(z * TWO_LOG2E);
                    const float q = __builtin_amdgcn_rcpf(e + 1.0f);
                    const float hv = fmaf(-2.0f, q, 1.0f);   // tanh(z)
                    if (r == 0) hf0 = hv;
                    if (r == 1) hf1 = hv;
                    if (r == 2) hf2 = hv;
                    if (r == 3) hf3 = hv;
                    const _Float16 hi = (_Float16)hv;
                    const _Float16 lo = (_Float16)(hv - (float)hi);
                    *(_Float16*)(wb +        woff[r]) = hi;
                    *(_Float16*)(wb + 2048 + woff[r]) = lo;
                }
            }
            __syncthreads();
        }
    }

    // ---- out[b] = sum_n h[b][n] * fc_w[n] + fc_b ----
    float v0 = hf0 * fcw, v1 = hf1 * fcw, v2 = hf2 * fcw, v3 = hf3 * fcw;
#pragma unroll
    for (int off = 1; off < 16; off <<= 1) {     // reduce over the 16 n's in wave
        v0 += __shfl_xor(v0, off, 64);
        v1 += __shfl_xor(v1, off, 64);
        v2 += __shfl_xor(v2, off, 64);
        v3 += __shfl_xor(v3, off, 64);
    }
    if (m16 == 0 && g < 2) {
        red[wid][4 * g + 0] = v0;
        red[wid][4 * g + 1] = v1;
        red[wid][4 * g + 2] = v2;
        red[wid][4 * g + 3] = v3;
    }
    __syncthreads();
    if (tid < GB) {
        const float o = red[0][tid] + red[1][tid] + red[2][tid] + red[3][tid];
        out[gb0 + tid] = o + fc_b[0];
    }
}

extern "C" void kernel_launch(void* const* d_in, const int* in_sizes, int n_in,
                              void* d_out, int out_size, void* d_ws, size_t ws_size,
                              hipStream_t stream)
{
    const float* x    = (const float*)d_in[0];
    const float* W_ih = (const float*)d_in[1];
    const float* W_hh = (const float*)d_in[2];
    const float* b_ih = (const float*)d_in[3];
    const float* b_hh = (const float*)d_in[4];
    const float* fc_w = (const float*)d_in[5];
    const float* fc_b = (const float*)d_in[6];
    float* out = (float*)d_out;

    const int B = in_sizes[0] / TDIM;          // x is (B, T, 1)
    const int blocks = B / GB;                 // 512 blocks -> 2 per CU

    rnn_mfma_ov2<<<blocks, 256, 0, stream>>>(
        x, W_ih, W_hh, b_ih, b_hh, fc_w, fc_b, out, B);
}